// Round 8
// baseline (1039.886 us; speedup 1.0000x reference)
//
#include <hip/hip_runtime.h>
#include <hip/hip_bf16.h>

typedef __attribute__((ext_vector_type(4))) float f32x4;
typedef __attribute__((ext_vector_type(8))) short short8;
typedef __attribute__((ext_vector_type(8))) unsigned short ushort8;
typedef __attribute__((ext_vector_type(4))) unsigned short u16x4;
typedef float f4a __attribute__((ext_vector_type(4), aligned(4)));

__device__ __forceinline__ unsigned short f2bf(float f) {
  unsigned int u = __float_as_uint(f);
  u += 0x7fffu + ((u >> 16) & 1u);   // RNE (finite inputs only)
  return (unsigned short)(u >> 16);
}

#define BARRIER do { asm volatile("" ::: "memory"); __builtin_amdgcn_s_barrier(); asm volatile("" ::: "memory"); } while(0)
#define LGKM    asm volatile("s_waitcnt lgkmcnt(0)" ::: "memory")
#define VMW(n)  asm volatile("s_waitcnt vmcnt(" #n ")" ::: "memory")

// ---------------- build xh = [emb[X], h] as bf16 [2048][4096] ----------------
__global__ __launch_bounds__(256) void k_build_xh(
    const int* __restrict__ X, const float* __restrict__ h,
    const float* __restrict__ emb, unsigned short* __restrict__ xh) {
  int b = blockIdx.x;
  int tid = threadIdx.x;
  int j0 = tid * 16;
  const float* src;
  if (j0 < 2048) {
    int xb = X[b];
    src = emb + (size_t)xb * 2048 + j0;
  } else {
    src = h + (size_t)b * 2048 + (j0 - 2048);
  }
  unsigned short* dst = xh + (size_t)b * 4096 + j0;
#pragma unroll
  for (int half = 0; half < 2; ++half) {
    float4 f0 = *(const float4*)(src + half * 8);
    float4 f1 = *(const float4*)(src + half * 8 + 4);
    ushort8 o;
    o[0] = f2bf(f0.x); o[1] = f2bf(f0.y); o[2] = f2bf(f0.z); o[3] = f2bf(f0.w);
    o[4] = f2bf(f1.x); o[5] = f2bf(f1.y); o[6] = f2bf(f1.z); o[7] = f2bf(f1.w);
    *(ushort8*)(dst + half * 8) = o;
  }
}

// ---------------- WgT: 4 gate weights -> bf16, transposed, gate-interleaved ----------------
__global__ __launch_bounds__(256) void k_cvt_wg(
    const float* __restrict__ W0, const float* __restrict__ W1,
    const float* __restrict__ W2, const float* __restrict__ W3,
    unsigned short* __restrict__ WT) {
  const int g = blockIdx.z;
  const float* W = (g == 0) ? W0 : (g == 1) ? W1 : (g == 2) ? W2 : W3;
  int tid = threadIdx.x, lane = tid & 63, w = tid >> 6;
  int n0 = blockIdx.x * 64, k0 = blockIdx.y * 64;
  int nb = n0 + 4 * (lane & 15);
  int kb = k0 + w * 16 + 4 * (lane >> 4);
  float v[4][4];
#pragma unroll
  for (int r = 0; r < 4; ++r) {
    f4a x = *(const f4a*)(W + (size_t)(kb + r) * 2048 + nb);
    v[r][0] = x.x; v[r][1] = x.y; v[r][2] = x.z; v[r][3] = x.w;
  }
#pragma unroll
  for (int e = 0; e < 4; ++e) {
    int col = nb + e;
    int row = ((col >> 6) << 8) + g * 64 + (col & 63);
    u16x4 o;
    o[0] = f2bf(v[0][e]); o[1] = f2bf(v[1][e]);
    o[2] = f2bf(v[2][e]); o[3] = f2bf(v[3][e]);
    *(u16x4*)(WT + (size_t)row * 4096 + kb) = o;
  }
}

// ---------------- transpose + convert: W f32 [K][Nin] -> WT bf16 [Nin][K] ----------------
__global__ __launch_bounds__(256) void k_cvt_t(
    const float* __restrict__ W, unsigned short* __restrict__ WT,
    int K, int Nin, int ldo) {
  int tid = threadIdx.x;
  int lane = tid & 63, w = tid >> 6;
  int n0 = blockIdx.x * 64, k0 = blockIdx.y * 64;
  int nb = n0 + 4 * (lane & 15);
  int kb = k0 + w * 16 + 4 * (lane >> 4);
  float v[4][4];
  if (nb + 3 < Nin) {
#pragma unroll
    for (int r = 0; r < 4; ++r) {
      f4a x = *(const f4a*)(W + (size_t)(kb + r) * Nin + nb);
      v[r][0] = x.x; v[r][1] = x.y; v[r][2] = x.z; v[r][3] = x.w;
    }
  } else {
#pragma unroll
    for (int r = 0; r < 4; ++r)
#pragma unroll
      for (int e = 0; e < 4; ++e)
        v[r][e] = (nb + e < Nin) ? W[(size_t)(kb + r) * Nin + nb + e] : 0.f;
  }
#pragma unroll
  for (int e = 0; e < 4; ++e) {
    if (nb + e < Nin) {
      u16x4 o;
      o[0] = f2bf(v[0][e]); o[1] = f2bf(v[1][e]);
      o[2] = f2bf(v[2][e]); o[3] = f2bf(v[3][e]);
      *(u16x4*)(WT + (size_t)(nb + e) * ldo + kb) = o;
    }
  }
}

// ---------------- 256x256 8-phase bf16 GEMM (16x16x32), job-paired ----------------
struct EpiP {
  const float *c, *b0, *b1, *b2, *b3;
  float *hnew, *cnew;
  unsigned short* hnbf;
};

__device__ __forceinline__ short8 ld_fragA(const unsigned char* smem, int buf, int half,
                                           int row_local, int ks, int lane) {
  unsigned kbyte = (unsigned)(ks * 64 + ((lane >> 4) << 4));
  unsigned off = (unsigned)(buf * 2 + half) * 16384u + (unsigned)row_local * 128u
               + (kbyte ^ (((unsigned)row_local & 7u) << 4));
  return *(const short8*)(smem + off);
}
__device__ __forceinline__ short8 ld_fragB(const unsigned char* smem, int buf, int half,
                                           int col_local, int ks, int lane) {
  unsigned kbyte = (unsigned)(ks * 64 + ((lane >> 4) << 4));
  unsigned off = 65536u + (unsigned)(buf * 2 + half) * 16384u + (unsigned)col_local * 128u
               + (kbyte ^ (((unsigned)col_local & 7u) << 4));
  return *(const short8*)(smem + off);
}

// y epilogue via per-wave 4KB scratch (offset 128KB..160KB): conflict-free rotation,
// no barriers, 256B-contiguous row stores.
__device__ __forceinline__ void epi_store_y(
    unsigned char* smem, const f32x4 (*acc)[4], const float* bias, float* C,
    int N, int mrow0, int ncolJ, int wid, int wr, int wc, int lane) {
  float* sw = (float*)(smem + 131072u + (unsigned)wid * 4096u);
  const int gcol = ncolJ + wc * 64 + lane;
  const float bv = bias[gcol];
#pragma unroll
  for (int mh = 0; mh < 2; ++mh)
#pragma unroll
    for (int mm = 0; mm < 4; ++mm) {
#pragma unroll
      for (int nn = 0; nn < 4; ++nn)
#pragma unroll
        for (int r = 0; r < 4; ++r) {
          int row16 = ((lane >> 4) << 2) + r;
          int cs = ((nn * 16 + (lane & 15)) + ((row16 >> 2) & 3) * 16) & 63;
          sw[row16 * 64 + cs] = acc[mh * 4 + mm][nn][r];
        }
#pragma unroll
      for (int rr = 0; rr < 16; ++rr) {
        int cs2 = (lane + ((rr >> 2) & 3) * 16) & 63;
        float v = sw[rr * 64 + cs2] + bv;
        int grow = mrow0 + wr * 128 + mh * 64 + mm * 16 + rr;
        C[(size_t)grow * N + gcol] = v;
      }
    }
}

template <int EPI, int JOBS>
__global__ __launch_bounds__(512, 1) void k_gemm256(
    const unsigned short* __restrict__ A, const unsigned short* __restrict__ Bt,
    const float* __restrict__ bias, float* __restrict__ C,
    int N, int K, int lda, int ldb, EpiP P) {
  __shared__ __align__(16) unsigned char smem[163840];
  const int tid = threadIdx.x, lane = tid & 63, wid = tid >> 6;
  const int wr = wid >> 2, wc = wid & 3;

  // XCD-aware bijective swizzle; gridDim.x == 8 (M-tiles vary fastest).
  int nwg = gridDim.x * gridDim.y;
  int o = blockIdx.y * gridDim.x + blockIdx.x;
  int q = nwg >> 3;
  int s = (o & 7) * q + (o >> 3);
  const int mrow0 = (s & 7) * 256;
  const int nidx = s >> 3;
  const int nc0 = nidx * 256;                 // job 0 col base
  const int nc1 = nc0 + (JOBS == 2 ? 24576 : 0);  // job 1 col base (96 tiles later)

  const int NKT = K >> 6;

  // ---- hoisted per-thread stage offsets (job-relative elements) ----
  unsigned vA[2], vB[2][2];
#pragma unroll
  for (int i = 0; i < 2; ++i) {
    unsigned phys = (unsigned)(i * 512 + tid) * 16u;
    unsigned logi = phys ^ (((phys >> 7) & 7u) << 4);
    unsigned r = logi >> 7;
    unsigned kbe = (logi & 127u) >> 1;
    vA[i] = r * (unsigned)lda + kbe;
#pragma unroll
    for (int hh = 0; hh < 2; ++hh)
      vB[hh][i] = (unsigned)(hh * 128 + (int)r) * (unsigned)ldb + kbe;
  }
  const unsigned short* Ab0 = A + (size_t)mrow0 * lda;
  const unsigned short* Ab1 = Ab0 + (size_t)128 * lda;
  const unsigned short* BtJ = Bt + (size_t)nc0 * ldb;

  f32x4 acc[8][4];
#pragma unroll
  for (int m = 0; m < 8; ++m)
#pragma unroll
    for (int n = 0; n < 4; ++n) acc[m][n] = {0.f, 0.f, 0.f, 0.f};

  short8 a_frag[4][2], b_frag[2][2][2];

#define STG(baseptr, v, ldsoff) __builtin_amdgcn_global_load_lds( \
    (const __attribute__((address_space(1))) void*)((baseptr) + (v)), \
    (__attribute__((address_space(3))) void*)(smem + (ldsoff)), 16, 0, 0)
#define ST_A_LO(buf, t) do { const unsigned short* _b0 = Ab0 + (size_t)(t) * 64; \
    const unsigned short* _b1 = Ab1 + (size_t)(t) * 64; \
    STG(_b0, vA[0], (unsigned)((buf) * 2 + 0) * 16384u + (unsigned)(wid * 1024)); \
    STG(_b1, vA[0], (unsigned)((buf) * 2 + 1) * 16384u + (unsigned)(wid * 1024)); } while (0)
#define ST_A_HI(buf, t) do { const unsigned short* _b0 = Ab0 + (size_t)(t) * 64; \
    const unsigned short* _b1 = Ab1 + (size_t)(t) * 64; \
    STG(_b0, vA[1], (unsigned)((buf) * 2 + 0) * 16384u + (unsigned)(8192 + wid * 1024)); \
    STG(_b1, vA[1], (unsigned)((buf) * 2 + 1) * 16384u + (unsigned)(8192 + wid * 1024)); } while (0)
#define ST_B(buf, hh, t) do { const unsigned short* _b = BtJ + (size_t)(t) * 64; \
    STG(_b, vB[hh][0], 65536u + (unsigned)((buf) * 2 + (hh)) * 16384u + (unsigned)(wid * 1024)); \
    STG(_b, vB[hh][1], 65536u + (unsigned)((buf) * 2 + (hh)) * 16384u + (unsigned)(8192 + wid * 1024)); } while (0)
#define RD_A(buf, mh) do { _Pragma("unroll") for (int mm = 0; mm < 4; ++mm) { int rl = (mh) * 64 + mm * 16 + (lane & 15); _Pragma("unroll") for (int ks = 0; ks < 2; ++ks) a_frag[mm][ks] = ld_fragA(smem, (buf), wr, rl, ks, lane); } } while (0)
#define RD_B(buf, nh) do { _Pragma("unroll") for (int nn = 0; nn < 2; ++nn) { int cl = (wc & 1) * 64 + (nh) * 32 + nn * 16 + (lane & 15); _Pragma("unroll") for (int ks = 0; ks < 2; ++ks) b_frag[nh][nn][ks] = ld_fragB(smem, (buf), (wc >> 1), cl, ks, lane); } } while (0)
#define MF(mh, nh) do { __builtin_amdgcn_s_setprio(1); _Pragma("unroll") for (int ks = 0; ks < 2; ++ks) _Pragma("unroll") for (int mm = 0; mm < 4; ++mm) _Pragma("unroll") for (int nn = 0; nn < 2; ++nn) acc[(mh) * 4 + mm][(nh) * 2 + nn] = __builtin_amdgcn_mfma_f32_16x16x32_bf16(a_frag[mm][ks], b_frag[(nh)][nn][ks], acc[(mh) * 4 + mm][(nh) * 2 + nn], 0, 0, 0); __builtin_amdgcn_s_setprio(0); } while (0)

#define ITER(X, Y, TA, TB) do { \
    RD_A(X, 0); RD_B(X, 0);                BARRIER; LGKM; MF(0, 0); BARRIER; \
    RD_B(X, 1); ST_A_LO(X, TA);            BARRIER; LGKM; MF(0, 1); BARRIER; \
    RD_A(X, 1); ST_B(X, 0, TA); ST_B(X, 1, TA); BARRIER; LGKM; MF(1, 1); BARRIER; \
    ST_A_HI(X, TA); VMW(8);                BARRIER; LGKM; MF(1, 0); BARRIER; \
    RD_A(Y, 0); RD_B(Y, 0);                BARRIER; LGKM; MF(0, 0); BARRIER; \
    RD_B(Y, 1); ST_A_LO(Y, TB);            BARRIER; LGKM; MF(0, 1); BARRIER; \
    RD_A(Y, 1); ST_B(Y, 0, TB); ST_B(Y, 1, TB); BARRIER; LGKM; MF(1, 1); BARRIER; \
    ST_A_HI(Y, TB); VMW(8);                BARRIER; LGKM; MF(1, 0); BARRIER; \
  } while (0)

#define PEEL_PLAIN(X, Y) do { \
    RD_A(X, 0); RD_B(X, 0);                BARRIER; LGKM; MF(0, 0); BARRIER; \
    RD_B(X, 1);                            BARRIER; LGKM; MF(0, 1); BARRIER; \
    RD_A(X, 1);                            BARRIER; LGKM; MF(1, 1); BARRIER; \
    VMW(0);                                BARRIER; LGKM; MF(1, 0); BARRIER; \
    RD_A(Y, 0); RD_B(Y, 0);                BARRIER; LGKM; MF(0, 0); BARRIER; \
    RD_B(Y, 1);                            BARRIER; LGKM; MF(0, 1); BARRIER; \
    RD_A(Y, 1);                            BARRIER; LGKM; MF(1, 1); BARRIER; \
                                           BARRIER; LGKM; MF(1, 0); BARRIER; \
  } while (0)

// Peel that also pre-stages the NEXT job's B for tiles TX (->buf X) and TY (->buf Y).
// BtJ must already point at the next job's columns. A-units stay valid (reverse-K reuse).
#define PEEL_STAGEB(X, Y, TX, TY) do { \
    RD_A(X, 0); RD_B(X, 0);                BARRIER; LGKM; MF(0, 0); BARRIER; \
    RD_B(X, 1);                            BARRIER; LGKM; MF(0, 1); BARRIER; \
    RD_A(X, 1); ST_B(X, 0, TX); ST_B(X, 1, TX); BARRIER; LGKM; MF(1, 1); BARRIER; \
    VMW(4);                                BARRIER; LGKM; MF(1, 0); BARRIER; \
    RD_A(Y, 0); RD_B(Y, 0);                BARRIER; LGKM; MF(0, 0); BARRIER; \
    RD_B(Y, 1);                            BARRIER; LGKM; MF(0, 1); BARRIER; \
    RD_A(Y, 1); ST_B(Y, 0, TY); ST_B(Y, 1, TY); BARRIER; LGKM; MF(1, 1); BARRIER; \
                                           BARRIER; LGKM; MF(1, 0); BARRIER; \
  } while (0)

  // Prologue: job0 tiles 0,1 fully staged; VMW(8) retires t0.
  ST_A_LO(0, 0); ST_A_HI(0, 0); ST_B(0, 0, 0); ST_B(0, 1, 0);
  ST_A_LO(1, 1); ST_A_HI(1, 1); ST_B(1, 0, 1); ST_B(1, 1, 1);
  VMW(8); BARRIER;

  // Job 0 main: forward K.
  for (int k = 0; k < (NKT - 2) / 2; ++k) ITER(0, 1, 2 * k + 2, 2 * k + 3);

  if constexpr (JOBS == 2) {
    // Job 0 peel + pre-stage job1's B for tiles NKT-2 (buf0) / NKT-1 (buf1).
    BtJ = Bt + (size_t)nc1 * ldb;
    PEEL_STAGEB(0, 1, NKT - 2, NKT - 1);
    // Job 0 epilogue from scratch region (bufs untouched; 8 loads in flight).
    epi_store_y(smem, acc, bias, C, N, mrow0, nc0, wid, wr, wc, lane);
#pragma unroll
    for (int m = 0; m < 8; ++m)
#pragma unroll
      for (int n = 0; n < 4; ++n) acc[m][n] = {0.f, 0.f, 0.f, 0.f};
    VMW(0); BARRIER;
    // Job 1 main: reverse K. buf1 holds NKT-1, buf0 holds NKT-2 (A reused, B fresh).
    for (int k = 0; k < (NKT - 2) / 2; ++k) ITER(1, 0, NKT - 3 - 2 * k, NKT - 4 - 2 * k);
    PEEL_PLAIN(1, 0);
    epi_store_y(smem, acc, bias, C, N, mrow0, nc1, wid, wr, wc, lane);
  } else {
    PEEL_PLAIN(0, 1);
    __syncthreads();
    if constexpr (EPI == 0) {
      epi_store_y(smem, acc, bias, C, N, mrow0, nc0, wid, wr, wc, lane);
    } else {
      // LSTM epilogue (gate-interleaved WgT): wave wc holds gate wc.
      float* ep = (float*)(smem + (unsigned)wr * 65536u);
      const int lt = (wid & 3) * 64 + lane;
      const int jj = lt & 63;
      const int rh = lt >> 6;
      const int gjj = (nc0 >> 2) + jj;
      const float bf_ = P.b0[gjj], big_ = P.b1[gjj], bog_ = P.b2[gjj], bi_ = P.b3[gjj];
#pragma unroll
      for (int mh = 0; mh < 2; ++mh) {
#pragma unroll
        for (int mm = 0; mm < 4; ++mm)
#pragma unroll
          for (int nn = 0; nn < 4; ++nn)
#pragma unroll
            for (int r = 0; r < 4; ++r) {
              int row = mm * 16 + ((lane >> 4) << 2) + r;
              int colv = nn * 16 + (lane & 15);
              int cs = (colv + ((row >> 2) & 3) * 16) & 63;
              ep[row * 256 + wc * 64 + cs] = acc[mh * 4 + mm][nn][r];
            }
        __syncthreads();
#pragma unroll
        for (int rr = 0; rr < 16; ++rr) {
          int row = rh * 16 + rr;
          int rot = (jj + ((row >> 2) & 3) * 16) & 63;
          float g0 = ep[row * 256 +   0 + rot];
          float g1 = ep[row * 256 +  64 + rot];
          float g2 = ep[row * 256 + 128 + rot];
          float g3 = ep[row * 256 + 192 + rot];
          int grow = mrow0 + wr * 128 + mh * 64 + row;
          size_t off = (size_t)grow * 2048 + gjj;
          float fg = 1.f / (1.f + expf(-(g0 + bf_)));
          float ig = 1.f / (1.f + expf(-(g1 + big_)));
          float og = 1.f / (1.f + expf(-(g2 + bog_)));
          float gt = tanhf(g3 + bi_);
          float cn = fg * P.c[off] + ig * gt;
          float hn = og * tanhf(cn);
          P.cnew[off] = cn;
          P.hnew[off] = hn;
          P.hnbf[off] = f2bf(hn);
        }
        __syncthreads();
      }
    }
  }
#undef STG
#undef ST_A_LO
#undef ST_A_HI
#undef ST_B
#undef RD_A
#undef RD_B
#undef MF
#undef ITER
#undef PEEL_PLAIN
#undef PEEL_STAGEB
}

// ---------------- m97-style 128x128 tail GEMM (N-edge) ----------------
__global__ __launch_bounds__(256) void k_gemm_tail(
    const unsigned short* __restrict__ A, const unsigned short* __restrict__ Bt,
    const float* __restrict__ bias, float* __restrict__ C,
    int N, int K, int lda, int ncol_base) {
  __shared__ unsigned short As[128 * 32];
  __shared__ unsigned short Bs[128 * 32];
  const int tid = threadIdx.x;
  const int lane = tid & 63;
  const int wid = tid >> 6;

  int nwg = gridDim.x * gridDim.y;
  int o = blockIdx.y * gridDim.x + blockIdx.x;
  int q = nwg >> 3;
  int s = (o & 7) * q + (o >> 3);
  const int mrow0 = (s / gridDim.x) * 128;
  const int ncol0 = ncol_base + (s % gridDim.x) * 128;

  f32x4 acc[4][4];
#pragma unroll
  for (int m = 0; m < 4; ++m)
#pragma unroll
    for (int n = 0; n < 4; ++n) acc[m][n] = {0.f, 0.f, 0.f, 0.f};

  const int wr = wid >> 1, wc = wid & 1;
  const int brow0 = wr * 64, bcol0 = wc * 64;

  int a_off[4], b_off[4];
#pragma unroll
  for (int m = 0; m < 4; ++m)
    a_off[m] = (brow0 + m * 16 + (lane & 15)) * 32 + ((lane >> 4) << 3);
#pragma unroll
  for (int n = 0; n < 4; ++n)
    b_off[n] = (bcol0 + n * 16 + (lane & 15)) * 32 + ((lane >> 4) << 3);

  for (int k0 = 0; k0 < K; k0 += 32) {
#pragma unroll
    for (int i = 0; i < 2; ++i) {
      int slot = i * 256 + tid;
      int r = slot >> 2, ck = slot & 3;
      unsigned short* la = As + (size_t)(i * 256 + wid * 64) * 8;
      unsigned short* lb = Bs + (size_t)(i * 256 + wid * 64) * 8;
      const unsigned short* ga = A + (size_t)(mrow0 + r) * lda + k0 + ck * 8;
      const unsigned short* gb = Bt + (size_t)(ncol0 + r) * K + k0 + ck * 8;
      __builtin_amdgcn_global_load_lds(
          (const __attribute__((address_space(1))) void*)ga,
          (__attribute__((address_space(3))) void*)la, 16, 0, 0);
      __builtin_amdgcn_global_load_lds(
          (const __attribute__((address_space(1))) void*)gb,
          (__attribute__((address_space(3))) void*)lb, 16, 0, 0);
    }
    __syncthreads();
    short8 af[4], bfr[4];
#pragma unroll
    for (int m = 0; m < 4; ++m) af[m] = *(const short8*)&As[a_off[m]];
#pragma unroll
    for (int n = 0; n < 4; ++n) bfr[n] = *(const short8*)&Bs[b_off[n]];
#pragma unroll
    for (int m = 0; m < 4; ++m)
#pragma unroll
      for (int n = 0; n < 4; ++n)
        acc[m][n] = __builtin_amdgcn_mfma_f32_16x16x32_bf16(af[m], bfr[n], acc[m][n], 0, 0, 0);
    __syncthreads();
  }

#pragma unroll
  for (int n = 0; n < 4; ++n) {
    int col = ncol0 + bcol0 + n * 16 + (lane & 15);
    if (col < N) {
      float bv = bias ? bias[col] : 0.f;
#pragma unroll
      for (int m = 0; m < 4; ++m) {
        int row0 = mrow0 + brow0 + m * 16 + ((lane >> 4) << 2);
        f32x4 v = acc[m][n];
#pragma unroll
        for (int r = 0; r < 4; ++r)
          C[(size_t)(row0 + r) * N + col] = v[r] + bv;
      }
    }
  }
}

extern "C" void kernel_launch(void* const* d_in, const int* in_sizes, int n_in,
                              void* d_out, int out_size, void* d_ws, size_t ws_size,
                              hipStream_t stream) {
  const int B = 2048, F = 2048, Ccls = 50257;
  const int NT = 50304;
  const int*   X    = (const int*)d_in[0];
  const float* h    = (const float*)d_in[1];
  const float* c    = (const float*)d_in[2];
  const float* emb  = (const float*)d_in[3];
  const float* Wf   = (const float*)d_in[4];
  const float* bf   = (const float*)d_in[5];
  const float* Wi   = (const float*)d_in[6];
  const float* bi   = (const float*)d_in[7];
  const float* Wig  = (const float*)d_in[8];
  const float* big  = (const float*)d_in[9];
  const float* Wog  = (const float*)d_in[10];
  const float* bog  = (const float*)d_in[11];
  const float* Wcls = (const float*)d_in[12];
  const float* bcls = (const float*)d_in[13];

  float* y    = (float*)d_out;                 // [B][C]
  float* hnew = y + (size_t)B * Ccls;          // [B][F]
  float* cnew = hnew + (size_t)B * F;          // [B][F]

  // ws: hnbf [0,8.4MB); xh [8.4,25.2); WgT [25.2,92.3); WclsT aliases [8.4,214.4)
  char* ws = (char*)d_ws;
  unsigned short* hnbf  = (unsigned short*)ws;
  unsigned short* xh    = (unsigned short*)(ws + 8388608);
  unsigned short* WgT   = (unsigned short*)(ws + 25165824);
  unsigned short* WclsT = (unsigned short*)(ws + 8388608);

  EpiP pz{nullptr, nullptr, nullptr, nullptr, nullptr, nullptr, nullptr, nullptr};

  // 1) xh = [emb[X], h] -> bf16
  k_build_xh<<<B, 256, 0, stream>>>(X, h, emb, xh);

  // 2) WgT (gate-interleaved, one launch)
  k_cvt_wg<<<dim3(32, 64, 4), 256, 0, stream>>>(Wf, Wig, Wog, Wi, WgT);

  // 3) gates GEMM + fused LSTM epilogue -> hnew, cnew (d_out) + hnbf (ws)
  EpiP pl{c, bf, big, bog, bi, hnew, cnew, hnbf};
  k_gemm256<1, 1><<<dim3(8, 32), 512, 0, stream>>>(
      xh, WgT, nullptr, nullptr, 8192, 4096, 4096, 4096, pl);

  // 4) WclsT = Wcls^T bf16 [NT rows alloc][2048]
  k_cvt_t<<<dim3(786, 32), 256, 0, stream>>>(Wcls, WclsT, 2048, Ccls, 2048);

  // 5) y main: cols [0, 49152) as 768 paired blocks (nidx, nidx+96) = 3 exact rounds
  k_gemm256<0, 2><<<dim3(8, 96), 512, 0, stream>>>(
      hnbf, WclsT, bcls, y, Ccls, 2048, 2048, 2048, pz);

  // 6) y tail: cols [49152, 50257) — 9 x 16 = 144 blocks (m97 128^2)
  k_gemm_tail<<<dim3(9, 16), 256, 0, stream>>>(
      hnbf, WclsT, bcls, y, Ccls, 2048, 2048, 49152);
}

// Round 9
// 787.215 us; speedup vs baseline: 1.3210x; 1.3210x over previous
//
#include <hip/hip_runtime.h>
#include <hip/hip_bf16.h>

typedef __attribute__((ext_vector_type(4))) float f32x4;
typedef __attribute__((ext_vector_type(8))) short short8;
typedef __attribute__((ext_vector_type(8))) unsigned short ushort8;
typedef __attribute__((ext_vector_type(4))) unsigned short u16x4;
typedef float f4a __attribute__((ext_vector_type(4), aligned(4)));

__device__ __forceinline__ unsigned short f2bf(float f) {
  unsigned int u = __float_as_uint(f);
  u += 0x7fffu + ((u >> 16) & 1u);   // RNE (finite inputs only)
  return (unsigned short)(u >> 16);
}

#define BARRIER do { asm volatile("" ::: "memory"); __builtin_amdgcn_s_barrier(); asm volatile("" ::: "memory"); } while(0)
#define LGKM    asm volatile("s_waitcnt lgkmcnt(0)" ::: "memory")
#define VMW(n)  asm volatile("s_waitcnt vmcnt(" #n ")" ::: "memory")

// ---------------- build xh = [emb[X], h] as bf16 [2048][4096] ----------------
__global__ __launch_bounds__(256) void k_build_xh(
    const int* __restrict__ X, const float* __restrict__ h,
    const float* __restrict__ emb, unsigned short* __restrict__ xh) {
  int b = blockIdx.x;
  int tid = threadIdx.x;
  int j0 = tid * 16;
  const float* src;
  if (j0 < 2048) {
    int xb = X[b];
    src = emb + (size_t)xb * 2048 + j0;
  } else {
    src = h + (size_t)b * 2048 + (j0 - 2048);
  }
  unsigned short* dst = xh + (size_t)b * 4096 + j0;
#pragma unroll
  for (int half = 0; half < 2; ++half) {
    float4 f0 = *(const float4*)(src + half * 8);
    float4 f1 = *(const float4*)(src + half * 8 + 4);
    ushort8 o;
    o[0] = f2bf(f0.x); o[1] = f2bf(f0.y); o[2] = f2bf(f0.z); o[3] = f2bf(f0.w);
    o[4] = f2bf(f1.x); o[5] = f2bf(f1.y); o[6] = f2bf(f1.z); o[7] = f2bf(f1.w);
    *(ushort8*)(dst + half * 8) = o;
  }
}

// ---------------- WgT: 4 gate weights -> bf16, transposed, gate-interleaved ----------------
// out row for (gate g, col j) = (j>>6)*256 + g*64 + (j&63); ld 4096.
__global__ __launch_bounds__(256) void k_cvt_wg(
    const float* __restrict__ W0, const float* __restrict__ W1,
    const float* __restrict__ W2, const float* __restrict__ W3,
    unsigned short* __restrict__ WT) {
  const int g = blockIdx.z;
  const float* W = (g == 0) ? W0 : (g == 1) ? W1 : (g == 2) ? W2 : W3;
  int tid = threadIdx.x, lane = tid & 63, w = tid >> 6;
  int n0 = blockIdx.x * 64, k0 = blockIdx.y * 64;
  int nb = n0 + 4 * (lane & 15);
  int kb = k0 + w * 16 + 4 * (lane >> 4);
  float v[4][4];
#pragma unroll
  for (int r = 0; r < 4; ++r) {
    f4a x = *(const f4a*)(W + (size_t)(kb + r) * 2048 + nb);
    v[r][0] = x.x; v[r][1] = x.y; v[r][2] = x.z; v[r][3] = x.w;
  }
#pragma unroll
  for (int e = 0; e < 4; ++e) {
    int col = nb + e;
    int row = ((col >> 6) << 8) + g * 64 + (col & 63);
    u16x4 o;
    o[0] = f2bf(v[0][e]); o[1] = f2bf(v[1][e]);
    o[2] = f2bf(v[2][e]); o[3] = f2bf(v[3][e]);
    *(u16x4*)(WT + (size_t)row * 4096 + kb) = o;
  }
}

// ---------------- transpose + convert: W f32 [K][Nin] -> WT bf16 [Nin][K] ----------------
__global__ __launch_bounds__(256) void k_cvt_t(
    const float* __restrict__ W, unsigned short* __restrict__ WT,
    int K, int Nin, int ldo) {
  int tid = threadIdx.x;
  int lane = tid & 63, w = tid >> 6;
  int n0 = blockIdx.x * 64, k0 = blockIdx.y * 64;
  int nb = n0 + 4 * (lane & 15);
  int kb = k0 + w * 16 + 4 * (lane >> 4);
  float v[4][4];
  if (nb + 3 < Nin) {
#pragma unroll
    for (int r = 0; r < 4; ++r) {
      f4a x = *(const f4a*)(W + (size_t)(kb + r) * Nin + nb);
      v[r][0] = x.x; v[r][1] = x.y; v[r][2] = x.z; v[r][3] = x.w;
    }
  } else {
#pragma unroll
    for (int r = 0; r < 4; ++r)
#pragma unroll
      for (int e = 0; e < 4; ++e)
        v[r][e] = (nb + e < Nin) ? W[(size_t)(kb + r) * Nin + nb + e] : 0.f;
  }
#pragma unroll
  for (int e = 0; e < 4; ++e) {
    if (nb + e < Nin) {
      u16x4 o;
      o[0] = f2bf(v[0][e]); o[1] = f2bf(v[1][e]);
      o[2] = f2bf(v[2][e]); o[3] = f2bf(v[3][e]);
      *(u16x4*)(WT + (size_t)(nb + e) * ldo + kb) = o;
    }
  }
}

// ---------------- 256x256 8-phase bf16 GEMM (T2+T3+T4+T5) ----------------
// Deep-pipeline ledger: half-iteration consuming tile u (buf=u&1) stages ALL
// 8 loads of tile u+2 into the same buf at earliest WAR-legal phases
// (A-lo after p1, B0+B1 after p2, A-hi after p3); VMW(8) at p4 retires
// exactly tile u+1, leaving u+2's 8 in flight (4-6 phase slack per load).
struct EpiP {
  const float *c, *b0, *b1, *b2, *b3;   // c, bias(f), bias(ig), bias(og), bias(g)
  float *hnew, *cnew;
  unsigned short* hnbf;
};

__device__ __forceinline__ short8 ld_fragA(const unsigned char* smem, int buf, int half,
                                           int row_local, int ks, int lane) {
  unsigned kbyte = (unsigned)(ks * 64 + ((lane >> 4) << 4));
  unsigned off = (unsigned)(buf * 2 + half) * 16384u + (unsigned)row_local * 128u
               + (kbyte ^ (((unsigned)row_local & 7u) << 4));
  return *(const short8*)(smem + off);
}
__device__ __forceinline__ short8 ld_fragB(const unsigned char* smem, int buf, int half,
                                           int col_local, int ks, int lane) {
  unsigned kbyte = (unsigned)(ks * 64 + ((lane >> 4) << 4));
  unsigned off = 65536u + (unsigned)(buf * 2 + half) * 16384u + (unsigned)col_local * 128u
               + (kbyte ^ (((unsigned)col_local & 7u) << 4));
  return *(const short8*)(smem + off);
}

template <int EPI>
__global__ __launch_bounds__(512, 1) void k_gemm256(
    const unsigned short* __restrict__ A, const unsigned short* __restrict__ Bt,
    const float* __restrict__ bias, float* __restrict__ C,
    int N, int K, int lda, int ldb, int rowmaxB, EpiP P) {
  __shared__ __align__(16) unsigned char smem[131072];
  const int tid = threadIdx.x, lane = tid & 63, wid = tid >> 6;
  const int wr = wid >> 2, wc = wid & 3;

  // XCD-aware bijective swizzle; gridDim.x == 8 (M-tiles vary fastest).
  int nwg = gridDim.x * gridDim.y;
  int o = blockIdx.y * gridDim.x + blockIdx.x;
  int q = nwg >> 3;
  int s = (o & 7) * q + (o >> 3);
  const int mrow0 = (s & 7) * 256;
  const int ncol0 = (s >> 3) * 256;

  const int NKT = K >> 6;

  // ---- hoisted per-thread stage offsets (elements) ----
  unsigned vA[2], vB[2][2];
#pragma unroll
  for (int i = 0; i < 2; ++i) {
    unsigned phys = (unsigned)(i * 512 + tid) * 16u;
    unsigned logi = phys ^ (((phys >> 7) & 7u) << 4);
    unsigned r = logi >> 7;
    unsigned kbe = (logi & 127u) >> 1;
    vA[i] = r * (unsigned)lda + kbe;
#pragma unroll
    for (int hh = 0; hh < 2; ++hh) {
      int br = ncol0 + hh * 128 + (int)r;
      br = (br > rowmaxB) ? rowmaxB : br;
      vB[hh][i] = (unsigned)br * (unsigned)ldb + kbe;
    }
  }
  const unsigned short* Ab0 = A + (size_t)mrow0 * lda;
  const unsigned short* Ab1 = Ab0 + (size_t)128 * lda;

  f32x4 acc[8][4];
#pragma unroll
  for (int m = 0; m < 8; ++m)
#pragma unroll
    for (int n = 0; n < 4; ++n) acc[m][n] = {0.f, 0.f, 0.f, 0.f};

  short8 a_frag[4][2], b_frag[2][2][2];

#define STG(baseptr, v, ldsoff) __builtin_amdgcn_global_load_lds( \
    (const __attribute__((address_space(1))) void*)((baseptr) + (v)), \
    (__attribute__((address_space(3))) void*)(smem + (ldsoff)), 16, 0, 0)
#define ST_A_LO(buf, t) do { const unsigned short* _b0 = Ab0 + (size_t)(t) * 64; \
    const unsigned short* _b1 = Ab1 + (size_t)(t) * 64; \
    STG(_b0, vA[0], (unsigned)((buf) * 2 + 0) * 16384u + (unsigned)(wid * 1024)); \
    STG(_b1, vA[0], (unsigned)((buf) * 2 + 1) * 16384u + (unsigned)(wid * 1024)); } while (0)
#define ST_A_HI(buf, t) do { const unsigned short* _b0 = Ab0 + (size_t)(t) * 64; \
    const unsigned short* _b1 = Ab1 + (size_t)(t) * 64; \
    STG(_b0, vA[1], (unsigned)((buf) * 2 + 0) * 16384u + (unsigned)(8192 + wid * 1024)); \
    STG(_b1, vA[1], (unsigned)((buf) * 2 + 1) * 16384u + (unsigned)(8192 + wid * 1024)); } while (0)
#define ST_B(buf, hh, t) do { const unsigned short* _b = Bt + (size_t)(t) * 64; \
    STG(_b, vB[hh][0], 65536u + (unsigned)((buf) * 2 + (hh)) * 16384u + (unsigned)(wid * 1024)); \
    STG(_b, vB[hh][1], 65536u + (unsigned)((buf) * 2 + (hh)) * 16384u + (unsigned)(8192 + wid * 1024)); } while (0)
#define RD_A(buf, mh) do { _Pragma("unroll") for (int mm = 0; mm < 4; ++mm) { int rl = (mh) * 64 + mm * 16 + (lane & 15); _Pragma("unroll") for (int ks = 0; ks < 2; ++ks) a_frag[mm][ks] = ld_fragA(smem, (buf), wr, rl, ks, lane); } } while (0)
#define RD_B(buf, nh) do { _Pragma("unroll") for (int nn = 0; nn < 2; ++nn) { int cl = (wc & 1) * 64 + (nh) * 32 + nn * 16 + (lane & 15); _Pragma("unroll") for (int ks = 0; ks < 2; ++ks) b_frag[nh][nn][ks] = ld_fragB(smem, (buf), (wc >> 1), cl, ks, lane); } } while (0)
#define MF(mh, nh) do { __builtin_amdgcn_s_setprio(1); _Pragma("unroll") for (int mm = 0; mm < 4; ++mm) _Pragma("unroll") for (int nn = 0; nn < 2; ++nn) _Pragma("unroll") for (int ks = 0; ks < 2; ++ks) acc[(mh) * 4 + mm][(nh) * 2 + nn] = __builtin_amdgcn_mfma_f32_16x16x32_bf16(a_frag[mm][ks], b_frag[(nh)][nn][ks], acc[(mh) * 4 + mm][(nh) * 2 + nn], 0, 0, 0); __builtin_amdgcn_s_setprio(0); } while (0)

  // Prologue: tiles 0 and 1 fully staged (16 loads); VMW(8) retires t0.
  ST_A_LO(0, 0); ST_A_HI(0, 0); ST_B(0, 0, 0); ST_B(0, 1, 0);
  ST_A_LO(1, 1); ST_A_HI(1, 1); ST_B(1, 0, 1); ST_B(1, 1, 1);
  VMW(8); BARRIER;

  for (int t0 = 0; t0 + 3 < NKT; t0 += 2) {
    // half A: consume buf0 (t0), stage t0+2 -> buf0
    RD_A(0, 0); RD_B(0, 0);
    BARRIER; LGKM; MF(0, 0); BARRIER;                  // p1
    RD_B(0, 1); ST_A_LO(0, t0 + 2);
    BARRIER; LGKM; MF(0, 1); BARRIER;                  // p2
    RD_A(0, 1); ST_B(0, 0, t0 + 2); ST_B(0, 1, t0 + 2);
    BARRIER; LGKM; MF(1, 1); BARRIER;                  // p3
    ST_A_HI(0, t0 + 2); VMW(8);
    BARRIER; LGKM; MF(1, 0); BARRIER;                  // p4 (t0+1 landed)
    // half B: consume buf1 (t0+1), stage t0+3 -> buf1
    RD_A(1, 0); RD_B(1, 0);
    BARRIER; LGKM; MF(0, 0); BARRIER;                  // p5
    RD_B(1, 1); ST_A_LO(1, t0 + 3);
    BARRIER; LGKM; MF(0, 1); BARRIER;                  // p6
    RD_A(1, 1); ST_B(1, 0, t0 + 3); ST_B(1, 1, t0 + 3);
    BARRIER; LGKM; MF(1, 1); BARRIER;                  // p7
    ST_A_HI(1, t0 + 3); VMW(8);
    BARRIER; LGKM; MF(1, 0); BARRIER;                  // p8 (t0+2 landed)
  }

  // Peeled final pair (t0 = NKT-2, t1 = NKT-1): no staging.
  {
    RD_A(0, 0); RD_B(0, 0);
    BARRIER; LGKM; MF(0, 0); BARRIER;
    RD_B(0, 1);
    BARRIER; LGKM; MF(0, 1); BARRIER;
    RD_A(0, 1);
    BARRIER; LGKM; MF(1, 1); BARRIER;
    VMW(0);
    BARRIER; LGKM; MF(1, 0); BARRIER;                  // t_{NKT-1} landed
    RD_A(1, 0); RD_B(1, 0);
    BARRIER; LGKM; MF(0, 0); BARRIER;
    RD_B(1, 1);
    BARRIER; LGKM; MF(0, 1); BARRIER;
    RD_A(1, 1);
    BARRIER; LGKM; MF(1, 1); BARRIER;
    BARRIER; LGKM; MF(1, 0); BARRIER;
  }

  __syncthreads();   // drain everything before smem reuse

  if constexpr (EPI == 0) {
    // y epilogue: per-wave LDS round-trip -> 256B-contiguous stores + bias.
    float* wlds = (float*)(smem + (unsigned)wid * 16384u);
    const int gcol = ncol0 + wc * 64 + lane;
    const bool cok = (gcol < N);
    const float bv = (bias != nullptr && cok) ? bias[gcol] : 0.f;
#pragma unroll
    for (int mh = 0; mh < 2; ++mh) {
#pragma unroll
      for (int mm = 0; mm < 4; ++mm)
#pragma unroll
        for (int nn = 0; nn < 4; ++nn)
#pragma unroll
          for (int r = 0; r < 4; ++r) {
            int row = mm * 16 + ((lane >> 4) << 2) + r;
            int colv = nn * 16 + (lane & 15);
            int cs = (colv + ((row >> 2) & 3) * 16) & 63;
            wlds[row * 64 + cs] = acc[mh * 4 + mm][nn][r];
          }
#pragma unroll 8
      for (int row = 0; row < 64; ++row) {
        int cs = (lane + ((row >> 2) & 3) * 16) & 63;
        float v = wlds[row * 64 + cs] + bv;
        int grow = mrow0 + wr * 128 + mh * 64 + row;
        if (cok) C[(size_t)grow * N + gcol] = v;
      }
    }
  } else {
    // LSTM epilogue: tile cols = 4 gates x 64 j's (gate-interleaved WgT).
    // Wave wc holds gate wc. Exchange via per-wr [64][256] f32 LDS region.
    float* ep = (float*)(smem + (unsigned)wr * 65536u);
    const int lt = (wid & 3) * 64 + lane;   // 0..255 within wr-group
    const int jj = lt & 63;
    const int rh = lt >> 6;                  // 0..3
    const int gjj = (ncol0 >> 2) + jj;       // global j
    const float bf_ = P.b0[gjj], big_ = P.b1[gjj], bog_ = P.b2[gjj], bi_ = P.b3[gjj];
#pragma unroll
    for (int mh = 0; mh < 2; ++mh) {
#pragma unroll
      for (int mm = 0; mm < 4; ++mm)
#pragma unroll
        for (int nn = 0; nn < 4; ++nn)
#pragma unroll
          for (int r = 0; r < 4; ++r) {
            int row = mm * 16 + ((lane >> 4) << 2) + r;
            int colv = nn * 16 + (lane & 15);
            int cs = (colv + ((row >> 2) & 3) * 16) & 63;
            ep[row * 256 + wc * 64 + cs] = acc[mh * 4 + mm][nn][r];
          }
      __syncthreads();
#pragma unroll
      for (int rr = 0; rr < 16; ++rr) {
        int row = rh * 16 + rr;
        int rot = (jj + ((row >> 2) & 3) * 16) & 63;
        float g0 = ep[row * 256 +   0 + rot];
        float g1 = ep[row * 256 +  64 + rot];
        float g2 = ep[row * 256 + 128 + rot];
        float g3 = ep[row * 256 + 192 + rot];
        int grow = mrow0 + wr * 128 + mh * 64 + row;
        size_t off = (size_t)grow * 2048 + gjj;
        float fg = 1.f / (1.f + expf(-(g0 + bf_)));
        float ig = 1.f / (1.f + expf(-(g1 + big_)));
        float og = 1.f / (1.f + expf(-(g2 + bog_)));
        float gt = tanhf(g3 + bi_);
        float cn = fg * P.c[off] + ig * gt;
        float hn = og * tanhf(cn);
        P.cnew[off] = cn;
        P.hnew[off] = hn;
        P.hnbf[off] = f2bf(hn);
      }
      __syncthreads();
    }
  }
#undef STG
#undef ST_A_LO
#undef ST_A_HI
#undef ST_B
#undef RD_A
#undef RD_B
#undef MF
}

// ---------------- m97-style 128x128 tail GEMM (N-edge) ----------------
__global__ __launch_bounds__(256) void k_gemm_tail(
    const unsigned short* __restrict__ A, const unsigned short* __restrict__ Bt,
    const float* __restrict__ bias, float* __restrict__ C,
    int N, int K, int lda, int ncol_base) {
  __shared__ unsigned short As[128 * 32];
  __shared__ unsigned short Bs[128 * 32];
  const int tid = threadIdx.x;
  const int lane = tid & 63;
  const int wid = tid >> 6;

  int nwg = gridDim.x * gridDim.y;
  int o = blockIdx.y * gridDim.x + blockIdx.x;
  int q = nwg >> 3;
  int s = (o & 7) * q + (o >> 3);
  const int mrow0 = (s / gridDim.x) * 128;
  const int ncol0 = ncol_base + (s % gridDim.x) * 128;

  f32x4 acc[4][4];
#pragma unroll
  for (int m = 0; m < 4; ++m)
#pragma unroll
    for (int n = 0; n < 4; ++n) acc[m][n] = {0.f, 0.f, 0.f, 0.f};

  const int wr = wid >> 1, wc = wid & 1;
  const int brow0 = wr * 64, bcol0 = wc * 64;

  int a_off[4], b_off[4];
#pragma unroll
  for (int m = 0; m < 4; ++m)
    a_off[m] = (brow0 + m * 16 + (lane & 15)) * 32 + ((lane >> 4) << 3);
#pragma unroll
  for (int n = 0; n < 4; ++n)
    b_off[n] = (bcol0 + n * 16 + (lane & 15)) * 32 + ((lane >> 4) << 3);

  for (int k0 = 0; k0 < K; k0 += 32) {
#pragma unroll
    for (int i = 0; i < 2; ++i) {
      int slot = i * 256 + tid;
      int r = slot >> 2, ck = slot & 3;
      unsigned short* la = As + (size_t)(i * 256 + wid * 64) * 8;
      unsigned short* lb = Bs + (size_t)(i * 256 + wid * 64) * 8;
      const unsigned short* ga = A + (size_t)(mrow0 + r) * lda + k0 + ck * 8;
      const unsigned short* gb = Bt + (size_t)(ncol0 + r) * K + k0 + ck * 8;
      __builtin_amdgcn_global_load_lds(
          (const __attribute__((address_space(1))) void*)ga,
          (__attribute__((address_space(3))) void*)la, 16, 0, 0);
      __builtin_amdgcn_global_load_lds(
          (const __attribute__((address_space(1))) void*)gb,
          (__attribute__((address_space(3))) void*)lb, 16, 0, 0);
    }
    __syncthreads();
    short8 af[4], bfr[4];
#pragma unroll
    for (int m = 0; m < 4; ++m) af[m] = *(const short8*)&As[a_off[m]];
#pragma unroll
    for (int n = 0; n < 4; ++n) bfr[n] = *(const short8*)&Bs[b_off[n]];
#pragma unroll
    for (int m = 0; m < 4; ++m)
#pragma unroll
      for (int n = 0; n < 4; ++n)
        acc[m][n] = __builtin_amdgcn_mfma_f32_16x16x32_bf16(af[m], bfr[n], acc[m][n], 0, 0, 0);
    __syncthreads();
  }

#pragma unroll
  for (int n = 0; n < 4; ++n) {
    int col = ncol0 + bcol0 + n * 16 + (lane & 15);
    if (col < N) {
      float bv = bias ? bias[col] : 0.f;
#pragma unroll
      for (int m = 0; m < 4; ++m) {
        int row0 = mrow0 + brow0 + m * 16 + ((lane >> 4) << 2);
        f32x4 v = acc[m][n];
#pragma unroll
        for (int r = 0; r < 4; ++r)
          C[(size_t)(row0 + r) * N + col] = v[r] + bv;
      }
    }
  }
}

extern "C" void kernel_launch(void* const* d_in, const int* in_sizes, int n_in,
                              void* d_out, int out_size, void* d_ws, size_t ws_size,
                              hipStream_t stream) {
  const int B = 2048, F = 2048, Ccls = 50257;
  const int NT = 50304;
  const int*   X    = (const int*)d_in[0];
  const float* h    = (const float*)d_in[1];
  const float* c    = (const float*)d_in[2];
  const float* emb  = (const float*)d_in[3];
  const float* Wf   = (const float*)d_in[4];
  const float* bf   = (const float*)d_in[5];
  const float* Wi   = (const float*)d_in[6];
  const float* bi   = (const float*)d_in[7];
  const float* Wig  = (const float*)d_in[8];
  const float* big  = (const float*)d_in[9];
  const float* Wog  = (const float*)d_in[10];
  const float* bog  = (const float*)d_in[11];
  const float* Wcls = (const float*)d_in[12];
  const float* bcls = (const float*)d_in[13];

  float* y    = (float*)d_out;                 // [B][C]
  float* hnew = y + (size_t)B * Ccls;          // [B][F]
  float* cnew = hnew + (size_t)B * F;          // [B][F]

  // ws: hnbf [0,8.4MB); xh [8.4,25.2); WgT [25.2,92.3); WclsT aliases [8.4,214.4)
  char* ws = (char*)d_ws;
  unsigned short* hnbf  = (unsigned short*)ws;
  unsigned short* xh    = (unsigned short*)(ws + 8388608);
  unsigned short* WgT   = (unsigned short*)(ws + 25165824);
  unsigned short* WclsT = (unsigned short*)(ws + 8388608);

  EpiP pz{nullptr, nullptr, nullptr, nullptr, nullptr, nullptr, nullptr, nullptr};

  // 1) xh = [emb[X], h] -> bf16
  k_build_xh<<<B, 256, 0, stream>>>(X, h, emb, xh);

  // 2) WgT (gate-interleaved, one launch)
  k_cvt_wg<<<dim3(32, 64, 4), 256, 0, stream>>>(Wf, Wig, Wog, Wi, WgT);

  // 3) gates GEMM + fused LSTM epilogue -> hnew, cnew (d_out) + hnbf (ws)
  EpiP pl{c, bf, big, bog, bi, hnew, cnew, hnbf};
  k_gemm256<1><<<dim3(8, 32), 512, 0, stream>>>(
      xh, WgT, nullptr, nullptr, 8192, 4096, 4096, 4096, 8191, pl);

  // 4) WclsT = Wcls^T bf16 [NT rows alloc][2048]
  k_cvt_t<<<dim3(786, 32), 256, 0, stream>>>(Wcls, WclsT, 2048, Ccls, 2048);

  // 5) y main: cols [0, 49152) — 1536 blocks = exactly 6 rounds
  k_gemm256<0><<<dim3(8, 192), 512, 0, stream>>>(
      hnbf, WclsT, bcls, y, Ccls, 2048, 2048, 2048, NT - 1, pz);

  // 6) y tail: cols [49152, 50257) — 9 x 16 = 144 blocks (m97 128^2)
  k_gemm_tail<<<dim3(9, 16), 256, 0, stream>>>(
      hnbf, WclsT, bcls, y, Ccls, 2048, 2048, 49152);
}